// Round 17
// baseline (224.330 us; speedup 1.0000x reference)
//
#include <hip/hip_runtime.h>

#define HID   32
#define INCH  128
#define OUTD  8
#define BATCH 512
#define TLEN  512
#define NGRP  16                 // 512 batches / 32 per group
#define NPROJ 512                // proj blocks (x4 items each = 2048)
#define ITEMS 2048

typedef __attribute__((ext_vector_type(2)))  int    i32x2;
typedef __attribute__((ext_vector_type(4)))  int    i32x4;
typedef __attribute__((ext_vector_type(8)))  short  short8_t;
typedef __attribute__((ext_vector_type(16))) float  f32x16_t;
typedef __attribute__((ext_vector_type(8)))  _Float16 half8_t;
typedef __attribute__((ext_vector_type(2)))  _Float16 h2v;

// Symmetric permlane32 idiom (HW-verified rounds 6/8/14)
__device__ __forceinline__ i32x2 swap32v(int a, int b)
{
#if __has_builtin(__builtin_amdgcn_permlane32_swap)
    return __builtin_amdgcn_permlane32_swap(a, b, false, false);
#else
    const int lane = threadIdx.x & 63;
    int as = __shfl_xor(a, 32, 64), bs = __shfl_xor(b, 32, 64);
    i32x2 r;
    r[0] = (lane < 32) ? bs : a;
    r[1] = (lane < 32) ? b  : as;
    return r;
#endif
}

__device__ __forceinline__ float swap32_add(float p)
{
    i32x2 r = swap32v(__float_as_int(p), __float_as_int(p));
    return __int_as_float(r[0]) + __int_as_float(r[1]);
}

// Broadcast half-`from`'s word to the whole wave (semantics-proof; R14 ✓)
__device__ __forceinline__ int bhalf(int x, int p, int from)
{
    const int z = (p == from) ? x : 0;
    i32x2 r = swap32v(z, z);
    return r[0] + r[1];
}

// Split fp32 -> bf16 hi (bit-truncate) + bf16 lo (truncated residual).
__device__ __forceinline__ void split8(const float4 f0, const float4 f1,
                                       short8_t* hi, short8_t* lo)
{
    float x[8] = {f0.x, f0.y, f0.z, f0.w, f1.x, f1.y, f1.z, f1.w};
    short8_t h, l;
    #pragma unroll
    for (int e = 0; e < 8; ++e) {
        const unsigned u  = __float_as_uint(x[e]);
        const unsigned hb = u & 0xFFFF0000u;
        h[e] = (short)(u >> 16);
        const float r = x[e] - __uint_as_float(hb);
        l[e] = (short)(__float_as_uint(r) >> 16);
    }
    *hi = h; *lo = l;
}

__device__ __forceinline__ unsigned pk2_rn(float a, float b)
{
    unsigned short ha = __builtin_bit_cast(unsigned short, (_Float16)a);
    unsigned short hb = __builtin_bit_cast(unsigned short, (_Float16)b);
    return (unsigned)ha | ((unsigned)hb << 16);
}

__device__ __forceinline__ unsigned cvt_relu_pk(float a, float b)
{
    const float ra = fmaxf(a, 0.0f);
    const float rb = fmaxf(b, 0.0f);
#if __has_builtin(__builtin_amdgcn_cvt_pkrtz)
    return __builtin_bit_cast(unsigned, __builtin_amdgcn_cvt_pkrtz(ra, rb));
#else
    return pk2_rn(ra, rb);
#endif
}

__device__ __forceinline__ float2 unpk2(unsigned u)
{
    h2v h = __builtin_bit_cast(h2v, u);
    return make_float2((float)h[0], (float)h[1]);
}

// ---------------------------------------------------------------------------
// Kernel 1: projection only. 512 blocks x 4 items; NO synchronization.
// xp row layout per (g,t): [0,1024) = lanes' A-halves, [1024,2048) B-halves.
// ---------------------------------------------------------------------------
__global__ __launch_bounds__(256, 2) void rnn_proj_kernel(
    const float* __restrict__ seq, const float* __restrict__ Wih,
    const float* __restrict__ bih, const float* __restrict__ bhh,
    char* __restrict__ ws)
{
    const int pid = blockIdx.x;
    const int tid = threadIdx.x;
    const int wv  = tid >> 6;
    const int l   = tid & 63;
    const int p   = l >> 5;

    short8_t whi[8], wlo[8];
    #pragma unroll
    for (int kb = 0; kb < 8; ++kb) {
        const float* wp = Wih + (l & 31) * INCH + kb * 16 + p * 8;
        split8(*(const float4*)wp, *(const float4*)(wp + 4), &whi[kb], &wlo[kb]);
    }
    float biasr[16];
    #pragma unroll
    for (int r = 0; r < 16; ++r) {
        const int i = (r & 3) + 8 * (r >> 2) + 4 * p;
        biasr[r] = bih[i] + bhh[i];
    }

    #pragma unroll
    for (int k = 0; k < 4; ++k) {
        const int item = pid + k * NPROJ;
        const int c   = item >> 6;
        const int g   = (item >> 2) & 15;
        const int sub = item & 3;
        const int t   = c * 16 + sub * 4 + wv;

        const float* sp = seq +
            ((size_t)(g * 32 + (l & 31)) * TLEN + t) * INCH + p * 8;

        f32x16_t acc;
        #pragma unroll
        for (int r = 0; r < 16; ++r) acc[r] = biasr[r];

        #pragma unroll
        for (int kb = 0; kb < 8; ++kb) {
            short8_t shi, slo;
            split8(*(const float4*)(sp + kb * 16),
                   *(const float4*)(sp + kb * 16 + 4), &shi, &slo);
            acc = __builtin_amdgcn_mfma_f32_32x32x16_bf16(whi[kb], shi, acc, 0, 0, 0);
            acc = __builtin_amdgcn_mfma_f32_32x32x16_bf16(whi[kb], slo, acc, 0, 0, 0);
            acc = __builtin_amdgcn_mfma_f32_32x32x16_bf16(wlo[kb], shi, acc, 0, 0, 0);
        }

        i32x4 oa, ob;
        oa[0] = (int)pk2_rn(acc[0],  acc[1]);
        oa[1] = (int)pk2_rn(acc[2],  acc[3]);
        oa[2] = (int)pk2_rn(acc[4],  acc[5]);
        oa[3] = (int)pk2_rn(acc[6],  acc[7]);
        ob[0] = (int)pk2_rn(acc[8],  acc[9]);
        ob[1] = (int)pk2_rn(acc[10], acc[11]);
        ob[2] = (int)pk2_rn(acc[12], acc[13]);
        ob[3] = (int)pk2_rn(acc[14], acc[15]);
        char* rowb = ws + (size_t)(g * TLEN + t) * 2048;
        *(i32x4*)(rowb + l * 16) = oa;
        *(i32x4*)(rowb + 1024 + l * 16) = ob;
    }
}

// ---------------------------------------------------------------------------
// Kernel 2: MFMA scan, 16 blocks x 1 wave, 8-deep register prefetch from the
// L3-resident xp. Zero atomics/fences/LDS. Measures the true MFMA chain.
// ---------------------------------------------------------------------------
__global__ __launch_bounds__(64, 1) void rnn_scan_kernel(
    const float* __restrict__ Whh, const float* __restrict__ Wfc,
    const float* __restrict__ bfc, float* __restrict__ out,
    const char* __restrict__ ws)
{
    const int g = blockIdx.x;
    const int l = threadIdx.x;
    const int p = l >> 5;

    half8_t wfA, wfB;
    #pragma unroll
    for (int e = 0; e < 8; ++e) {
        wfA[e] = (_Float16)Whh[(l & 31) * HID + 8 * p + e];
        wfB[e] = (_Float16)Whh[(l & 31) * HID + 16 + 8 * p + e];
    }

    i32x4 hAw = {0, 0, 0, 0}, hBw = {0, 0, 0, 0};
    f32x16_t Dl;
    #pragma unroll
    for (int r = 0; r < 16; ++r) Dl[r] = 0.0f;

    const char* xg = ws + (size_t)g * (TLEN * 2048);

    // prologue: prefetch t = 0..7
    i32x4 P0a, P0b, P1a, P1b, P2a, P2b, P3a, P3b;
    i32x4 P4a, P4b, P5a, P5b, P6a, P6b, P7a, P7b;
#define LD(J, T) { const char* rb = xg + (size_t)(T) * 2048 + l * 16;         \
                   P##J##a = *(const i32x4*)rb;                               \
                   P##J##b = *(const i32x4*)(rb + 1024); }
    LD(0, 0) LD(1, 1) LD(2, 2) LD(3, 3) LD(4, 4) LD(5, 5) LD(6, 6) LD(7, 7)

#define STEP(XA, XB)                                                          \
    {                                                                         \
        f32x16_t Cv;                                                          \
        float2 f;                                                             \
        f = unpk2((unsigned)XA[0]); Cv[0]  = f.x; Cv[1]  = f.y;               \
        f = unpk2((unsigned)XA[1]); Cv[2]  = f.x; Cv[3]  = f.y;               \
        f = unpk2((unsigned)XA[2]); Cv[4]  = f.x; Cv[5]  = f.y;               \
        f = unpk2((unsigned)XA[3]); Cv[6]  = f.x; Cv[7]  = f.y;               \
        f = unpk2((unsigned)XB[0]); Cv[8]  = f.x; Cv[9]  = f.y;               \
        f = unpk2((unsigned)XB[1]); Cv[10] = f.x; Cv[11] = f.y;               \
        f = unpk2((unsigned)XB[2]); Cv[12] = f.x; Cv[13] = f.y;               \
        f = unpk2((unsigned)XB[3]); Cv[14] = f.x; Cv[15] = f.y;               \
        f32x16_t U = __builtin_amdgcn_mfma_f32_32x32x16_f16(                  \
            wfB, __builtin_bit_cast(half8_t, hBw), Cv, 0, 0, 0);              \
        Dl = __builtin_amdgcn_mfma_f32_32x32x16_f16(                          \
            wfA, __builtin_bit_cast(half8_t, hAw), U, 0, 0, 0);               \
        const int w0 = (int)cvt_relu_pk(Dl[0],  Dl[1]);                       \
        const int w1 = (int)cvt_relu_pk(Dl[2],  Dl[3]);                       \
        const int w2 = (int)cvt_relu_pk(Dl[4],  Dl[5]);                       \
        const int w3 = (int)cvt_relu_pk(Dl[6],  Dl[7]);                       \
        const int w4 = (int)cvt_relu_pk(Dl[8],  Dl[9]);                       \
        const int w5 = (int)cvt_relu_pk(Dl[10], Dl[11]);                      \
        const int w6 = (int)cvt_relu_pk(Dl[12], Dl[13]);                      \
        const int w7 = (int)cvt_relu_pk(Dl[14], Dl[15]);                      \
        const int b02 = bhalf(w2, p, 0);                                      \
        const int b03 = bhalf(w3, p, 0);                                      \
        const int b10 = bhalf(w0, p, 1);                                      \
        const int b11 = bhalf(w1, p, 1);                                      \
        const int b06 = bhalf(w6, p, 0);                                      \
        const int b07 = bhalf(w7, p, 0);                                      \
        const int b14 = bhalf(w4, p, 1);                                      \
        const int b15 = bhalf(w5, p, 1);                                      \
        hAw[0] = p ? b02 : w0;                                                \
        hAw[1] = p ? b03 : w1;                                                \
        hAw[2] = p ? w2  : b10;                                               \
        hAw[3] = p ? w3  : b11;                                               \
        hBw[0] = p ? b06 : w4;                                                \
        hBw[1] = p ? b07 : w5;                                                \
        hBw[2] = p ? w6  : b14;                                               \
        hBw[3] = p ? w7  : b15;                                               \
    }

    for (int tb = 0; tb < TLEN; tb += 8) {
#define QSTEP(J)                                                              \
        STEP(P##J##a, P##J##b)                                                \
        { const int tn = tb + 8 + (J);                                        \
          if (tn < TLEN) LD(J, tn) }
        QSTEP(0) QSTEP(1) QSTEP(2) QSTEP(3)
        QSTEP(4) QSTEP(5) QSTEP(6) QSTEP(7)
#undef QSTEP
    }
#undef STEP
#undef LD

    float hr[16];
    #pragma unroll
    for (int r = 0; r < 16; ++r) hr[r] = fmaxf(Dl[r], 0.0f);

    float po[8];
    #pragma unroll
    for (int o = 0; o < OUTD; ++o) {
        float s = 0.0f;
        #pragma unroll
        for (int r = 0; r < 16; ++r) {
            const int i = (r & 3) + 8 * (r >> 2) + 4 * p;
            s = fmaf(hr[r], Wfc[o * HID + i], s);
        }
        po[o] = swap32_add(s) + bfc[o];
    }
    if (l < 32) {
        float4 v0 = make_float4(po[0], po[1], po[2], po[3]);
        float4 v1 = make_float4(po[4], po[5], po[6], po[7]);
        float* op = out + (size_t)(g * 32 + l) * OUTD;
        *(float4*)op = v0;
        *(float4*)(op + 4) = v1;
    }
}

extern "C" void kernel_launch(void* const* d_in, const int* in_sizes, int n_in,
                              void* d_out, int out_size, void* d_ws, size_t ws_size,
                              hipStream_t stream) {
    const float* seq = (const float*)d_in[0];
    const float* Wih = (const float*)d_in[1];
    const float* Whh = (const float*)d_in[2];
    const float* bih = (const float*)d_in[3];
    const float* bhh = (const float*)d_in[4];
    const float* Wfc = (const float*)d_in[5];
    const float* bfc = (const float*)d_in[6];

    rnn_proj_kernel<<<dim3(NPROJ), dim3(256), 0, stream>>>(
        seq, Wih, bih, bhh, (char*)d_ws);
    rnn_scan_kernel<<<dim3(NGRP), dim3(64), 0, stream>>>(
        Whh, Wfc, bfc, (float*)d_out, (const char*)d_ws);
}

// Round 18
// 51.850 us; speedup vs baseline: 4.3265x; 4.3265x over previous
//
#include <hip/hip_runtime.h>

#define HID   32
#define INCH  128
#define OUTD  8
#define BATCH 512
#define TLEN  512
#define TT    32
#define NCHUNK (TLEN / TT)

typedef __attribute__((ext_vector_type(2)))  float  f32x2;
typedef __attribute__((ext_vector_type(4)))  float  vf4;
typedef __attribute__((ext_vector_type(8)))  short  short8_t;
typedef __attribute__((ext_vector_type(16))) float  f32x16_t;
typedef __attribute__((ext_vector_type(2)))  int    i32x2;

// p_own + p[lane^32]  (HW-verified rounds 6/8/14)
__device__ __forceinline__ float swap32_add(float p)
{
#if __has_builtin(__builtin_amdgcn_permlane32_swap)
    i32x2 r = __builtin_amdgcn_permlane32_swap(
        __float_as_int(p), __float_as_int(p), false, false);
    return __int_as_float(r[0]) + __int_as_float(r[1]);
#else
    return p + __shfl_xor(p, 32, 64);
#endif
}

// Split fp32 -> bf16 hi (bit-truncate) + bf16 lo (truncated residual).
__device__ __forceinline__ void split8(const float4 f0, const float4 f1,
                                       short8_t* hi, short8_t* lo)
{
    float x[8] = {f0.x, f0.y, f0.z, f0.w, f1.x, f1.y, f1.z, f1.w};
    short8_t h, l;
    #pragma unroll
    for (int e = 0; e < 8; ++e) {
        const unsigned u  = __float_as_uint(x[e]);
        const unsigned hb = u & 0xFFFF0000u;
        h[e] = (short)(u >> 16);
        const float r = x[e] - __uint_as_float(hb);
        l[e] = (short)(__float_as_uint(r) >> 16);
    }
    *hi = h; *lo = l;
}

// ---------------------------------------------------------------------------
// One block per batch row; 2 waves. (Round-10 kernel — best measured overall:
// 51.8 µs. Scan chain = 243 cyc/step, the best of 6 HW-measured exchange
// mechanisms; proj MFMA fully hidden behind it.)
//   wave 0 (scan): h = relu(x_t + W_hh h), fp32.
//     - j-range split across half-waves: 4 ds_read_b128 on the chain
//     - cross-half combine via permlane32_swap (VALU)
//     - xv folded into half-0's partial via cndmask seed (off-chain)
//     - x prefetch issued before the h-write (in-order LDS pipe)
//   wave 1 (proj): split-bf16 MFMA 32x32x128 GEMM per chunk; D stored
//     transposed (XOR-swizzled) as 4x ds_write_b128 per lane.
// ---------------------------------------------------------------------------
__global__ __launch_bounds__(128, 1) void rnn_fused_kernel(
    const float* __restrict__ seq, const float* __restrict__ Wih,
    const float* __restrict__ Whh, const float* __restrict__ bih,
    const float* __restrict__ bhh, const float* __restrict__ Wfc,
    const float* __restrict__ bfc, float* __restrict__ out)
{
    __shared__ __align__(16) float xpb[2][TT * HID];   // transposed [ch][t], 8 KB
    __shared__ __align__(16) float hlds[64];           // 2 copies of h

    const int tid  = threadIdx.x;
    const int wid  = tid >> 6;
    const int l    = tid & 63;
    const int row  = blockIdx.x;

    if (wid == 0) {
        // ============================ SCAN ============================
        const int ch    = l & 31;
        const int half  = l >> 5;
        const int jbase = half * 16;
        const int m     = 4 * (ch & 7);                 // x swizzle (dwords)

        // W_hh[ch][jbase .. jbase+15] as 8 f32x2
        f32x2 w2[8];
        {
            const vf4* W4 = (const vf4*)(Whh + ch * HID + jbase);
            #pragma unroll
            for (int q = 0; q < 4; ++q) {
                const vf4 t = W4[q];
                w2[2 * q + 0] = t.xy;
                w2[2 * q + 1] = t.zw;
            }
        }

        hlds[l] = 0.0f;                                 // h0 = 0 (both copies)
        // low half reads h[0..15] (copy 0), high half h[16..31] (copy 1)
        const vf4* h4 = (const vf4*)&hlds[half * 48];

        __builtin_amdgcn_s_setprio(1);
        for (int c = 0; c < NCHUNK; ++c) {
            __syncthreads();                            // chunk c published
            const float* xb = xpb[c & 1] + ch * TT;     // my channel's column
            vf4 xq[8];
            xq[0] = *(const vf4*)(xb + m);              // x[0..3]

            #pragma unroll
            for (int tt = 0; tt < TT; ++tt) {
                const float xv = xq[tt >> 2][tt & 3];
                const float xs = half ? 0.0f : xv;      // cndmask, off-chain
                const vf4 h0 = h4[0];
                const vf4 h1 = h4[1];
                const vf4 h2 = h4[2];
                const vf4 h3 = h4[3];
                // x prefetch: issued after the h-reads, before the h-write,
                // so it completes inside the FMA window
                if (tt < 7)
                    xq[tt + 1] = *(const vf4*)(xb + (((tt + 1) * 4) ^ m));
                f32x2 seed; seed.x = xs; seed.y = 0.0f;
                f32x2 a0 = w2[0] * h0.xy + seed;
                f32x2 a1 = w2[1] * h0.zw;
                a0 = w2[2] * h1.xy + a0;
                a1 = w2[3] * h1.zw + a1;
                a0 = w2[4] * h2.xy + a0;
                a1 = w2[5] * h2.zw + a1;
                a0 = w2[6] * h3.xy + a0;
                a1 = w2[7] * h3.zw + a1;
                const f32x2 s2 = a0 + a1;
                const float p = s2.x + s2.y;            // half partial (+xv)
                const float tot = swap32_add(p);        // own + partner
                const float hn = fmaxf(tot, 0.0f);
                hlds[l] = hn;                           // publish for next step
            }
        }
        __builtin_amdgcn_s_setprio(0);

        // FC head: lane o (0..7) computes out[row][o] from hlds copy 0.
        if (l < OUTD) {
            float s = bfc[l];
            #pragma unroll
            for (int j = 0; j < HID; ++j)
                s = fmaf(hlds[j], Wfc[l * HID + j], s);
            out[row * OUTD + l] = s;
        }
    } else {
        // ============================ PROJ ============================
        const int trow  = l & 31;          // timestep within chunk (A row)
        const int khalf = l >> 5;          // k-half selector
        const int irow  = l & 31;          // channel (B col / W_ih row)

        short8_t whi[8], wlo[8];
        #pragma unroll
        for (int kb = 0; kb < 8; ++kb) {
            const float* wp = Wih + irow * INCH + kb * 16 + khalf * 8;
            const float4 f0 = *(const float4*)(wp);
            const float4 f1 = *(const float4*)(wp + 4);
            split8(f0, f1, &whi[kb], &wlo[kb]);
        }
        const float biasv = bih[irow] + bhh[irow];
        const int m2 = 4 * (irow & 7);                  // store swizzle

        for (int c = 0; c < NCHUNK; ++c) {
            const float* sp = seq +
                ((size_t)row * TLEN + (size_t)c * TT + trow) * INCH + khalf * 8;
            short8_t ahi[8], alo[8];
            #pragma unroll
            for (int kb = 0; kb < 8; ++kb) {
                const float4 f0 = *(const float4*)(sp + kb * 16);
                const float4 f1 = *(const float4*)(sp + kb * 16 + 4);
                split8(f0, f1, &ahi[kb], &alo[kb]);
            }

            f32x16_t acc;
            #pragma unroll
            for (int r2 = 0; r2 < 16; ++r2) acc[r2] = biasv;
            #pragma unroll
            for (int kb = 0; kb < 8; ++kb) {
                acc = __builtin_amdgcn_mfma_f32_32x32x16_bf16(ahi[kb], whi[kb], acc, 0, 0, 0);
                acc = __builtin_amdgcn_mfma_f32_32x32x16_bf16(ahi[kb], wlo[kb], acc, 0, 0, 0);
                acc = __builtin_amdgcn_mfma_f32_32x32x16_bf16(alo[kb], whi[kb], acc, 0, 0, 0);
            }

            // D: lane holds 16 timesteps of channel irow -> transposed store,
            // 4x ds_write_b128 at t0 = 8g + 4*khalf (XOR-swizzled)
            float* xbT = xpb[c & 1] + irow * TT;
            #pragma unroll
            for (int g = 0; g < 4; ++g) {
                const int t0 = 8 * g + 4 * khalf;
                vf4 v;
                v.x = acc[4 * g + 0]; v.y = acc[4 * g + 1];
                v.z = acc[4 * g + 2]; v.w = acc[4 * g + 3];
                *(vf4*)(xbT + (t0 ^ m2)) = v;
            }
            __syncthreads();                            // publish chunk c
        }
    }
}

extern "C" void kernel_launch(void* const* d_in, const int* in_sizes, int n_in,
                              void* d_out, int out_size, void* d_ws, size_t ws_size,
                              hipStream_t stream) {
    const float* seq = (const float*)d_in[0];
    const float* Wih = (const float*)d_in[1];
    const float* Whh = (const float*)d_in[2];
    const float* bih = (const float*)d_in[3];
    const float* bhh = (const float*)d_in[4];
    const float* Wfc = (const float*)d_in[5];
    const float* bfc = (const float*)d_in[6];

    rnn_fused_kernel<<<dim3(BATCH), dim3(128), 0, stream>>>(
        seq, Wih, Whh, bih, bhh, Wfc, bfc, (float*)d_out);
}